// Round 1
// baseline (140.591 us; speedup 1.0000x reference)
//
#include <hip/hip_runtime.h>

#define IN_F 256
#define HID 512
#define OUT_F 2048
#define N_HEADS 8
#define BATCH 4096

typedef __bf16 bf16_t;
typedef bf16_t bf16x8 __attribute__((ext_vector_type(8)));
typedef float f32x4 __attribute__((ext_vector_type(4)));
typedef unsigned short ushort8 __attribute__((ext_vector_type(8)));

typedef __attribute__((address_space(1))) const unsigned int gu32;
typedef __attribute__((address_space(3))) unsigned int lu32;

__device__ inline unsigned short f2bf(float f) {
  union { float f; unsigned u; } v; v.f = f;
  unsigned u = v.u;
  unsigned r = (u + 0x7FFFu + ((u >> 16) & 1u)) >> 16;  // RNE
  return (unsigned short)r;
}

// ---------------- W transpose 64x64 tile (fp32 [K][N] -> bf16 [N][K]) ----------
__device__ inline void transpose64(const float* __restrict__ W,
                                   unsigned short* __restrict__ Wt,
                                   int K, int N, int b, int nt, int kt,
                                   float (*tile)[65]) {
  int per_head = nt * kt;
  int h = b / per_head;
  int rem = b % per_head;
  int n0 = (rem % nt) * 64;
  int k0 = (rem / nt) * 64;
  const float* Wh = W + (size_t)h * K * N;
  unsigned short* Wth = Wt + (size_t)h * K * N;
  int c = threadIdx.x & 63;
  int r0 = threadIdx.x >> 6;  // 0..3
  for (int rr = r0; rr < 64; rr += 4)
    tile[rr][c] = Wh[(size_t)(k0 + rr) * N + n0 + c];
  __syncthreads();
  for (int rr = r0; rr < 64; rr += 4)
    Wth[(size_t)(n0 + rr) * K + k0 + c] = f2bf(tile[c][rr]);
}

// ---------------- fused prep: bucket (block 0) + W1/W2 transpose --------------
// grid: [0]          bucket rows by head (256 threads, two passes over idx)
//       [1,257)      W1 transpose 64x64 tiles (8 n x 4 k x 8 h = 256)
//       [257,2305)   W2 transpose 64x64 tiles (32 n x 8 k x 8 h = 2048)
__global__ __launch_bounds__(256) void prep_kernel(const int* __restrict__ idx,
                                                   int* __restrict__ order,
                                                   int* __restrict__ offsets,
                                                   const float* __restrict__ W1,
                                                   unsigned short* __restrict__ W1t,
                                                   const float* __restrict__ W2,
                                                   unsigned short* __restrict__ W2t) {
  __shared__ float tile[64][65];
  __shared__ int cnt[N_HEADS];
  __shared__ int base[N_HEADS + 1];
  __shared__ int cur[N_HEADS];
  int b = blockIdx.x;
  if (b == 0) {
    int tid = threadIdx.x;
    if (tid < N_HEADS) cnt[tid] = 0;
    __syncthreads();
    for (int i = tid; i < BATCH; i += 256) atomicAdd(&cnt[idx[i]], 1);
    __syncthreads();
    if (tid == 0) {
      int acc = 0;
      for (int h = 0; h < N_HEADS; ++h) { base[h] = acc; cur[h] = acc; acc += cnt[h]; }
      base[N_HEADS] = acc;
    }
    __syncthreads();
    if (tid < N_HEADS + 1) offsets[tid] = base[tid];
    for (int i = tid; i < BATCH; i += 256) {
      int pos = atomicAdd(&cur[idx[i]], 1);
      order[pos] = i;
    }
  } else if (b < 257) {
    transpose64(W1, W1t, IN_F, HID, b - 1, HID / 64, IN_F / 64, tile);
  } else {
    transpose64(W2, W2t, HID, OUT_F, b - 257, OUT_F / 64, HID / 64, tile);
  }
}

// ---------------- grouped GEMM, 128x128 tile, BK=64, XOR-swizzled LDS ---------
// A (GATHER_A=0): [BATCH][K] bf16 sorted rows, staged via global_load_lds with
//                 pre-swizzled source segment (rule 21: linear dest + inv-swz src).
// A (GATHER_A=1): gathered from fp32 Xf via order[], cvt->bf16, swizzled ds_write.
// B: Wt [H][NTOT][K] bf16, global_load_lds with pre-swizzled source segment.
// LDS layout [row][64] bf16, segment s (16B) stored at phys s ^ (row&7):
// conflict-free ds_read_b128 fragments (8 distinct bank-quads x 8 rows = floor).
// EPI==0: Hout[p][n] = bf16(relu(acc+bias))  (sorted).  EPI==1: scatter fp32.
template <int K, int NTOT, int EPI, int GATHER_A>
__global__ __launch_bounds__(256) void gemm_kernel(const unsigned short* __restrict__ A,
                                                   const float* __restrict__ Xf,
                                                   const unsigned short* __restrict__ Wt,
                                                   const float* __restrict__ bias,
                                                   const int* __restrict__ offsets,
                                                   const int* __restrict__ order,
                                                   unsigned short* __restrict__ Hout,
                                                   float* __restrict__ Out) {
  constexpr int BM = 128, BN = 128, BK = 64;
  __shared__ __align__(16) unsigned short As[BM * BK];
  __shared__ __align__(16) unsigned short Bs[BN * BK];

  int my = blockIdx.y;
  int head = -1, row0 = 0, rows = 0, acc_t = 0;
#pragma unroll
  for (int h = 0; h < N_HEADS; ++h) {
    int o0 = offsets[h], o1 = offsets[h + 1];
    int cnt = o1 - o0;
    int t = (cnt + BM - 1) / BM;
    if (head < 0 && my < acc_t + t) {
      head = h;
      int lt = my - acc_t;
      row0 = o0 + lt * BM;
      rows = min(BM, cnt - lt * BM);
    }
    acc_t += t;
  }
  if (head < 0) return;

  int n0 = blockIdx.x * BN;
  const unsigned short* Bh = Wt + (size_t)head * (size_t)NTOT * K;

  int tid = threadIdx.x;
  int wave = tid >> 6;
  int lane = tid & 63;
  int q = lane >> 4;
  int l16 = lane & 15;
  int w_m = wave >> 1, w_n = wave & 1;

  // staging geometry: instr i covers rows [wave*32 + i*8, +8), 8 segs of 16B/row
  int srow = lane >> 3;   // 0..7 : row within 8-row group (= row & 7)
  int seg = lane & 7;     // physical 16B segment in LDS row
  int segl = seg ^ srow;  // logical (global source) segment

  const unsigned short* bptr[4];
#pragma unroll
  for (int i = 0; i < 4; ++i) {
    int rl = wave * 32 + i * 8 + srow;
    bptr[i] = Bh + (size_t)(n0 + rl) * K + segl * 8;
  }

  const unsigned short* aptr[4];
  const float* gptr[4];
#pragma unroll
  for (int i = 0; i < 4; ++i) {
    int rl = wave * 32 + i * 8 + srow;
    int pr = row0 + min(rl, rows - 1);
    if (GATHER_A) {
      gptr[i] = Xf + (size_t)order[pr] * K + segl * 8;
      aptr[i] = nullptr;
    } else {
      aptr[i] = A + (size_t)pr * K + segl * 8;
      gptr[i] = nullptr;
    }
  }

  f32x4 acc[4][4];
#pragma unroll
  for (int i = 0; i < 4; ++i)
#pragma unroll
    for (int j = 0; j < 4; ++j) acc[i][j] = (f32x4){0.f, 0.f, 0.f, 0.f};

  for (int k0 = 0; k0 < K; k0 += BK) {
#pragma unroll
    for (int i = 0; i < 4; ++i) {
      __builtin_amdgcn_global_load_lds((gu32*)bptr[i], (lu32*)(Bs + wave * 2048 + i * 512), 16, 0, 0);
      bptr[i] += BK;
    }
    if (GATHER_A == 0) {
#pragma unroll
      for (int i = 0; i < 4; ++i) {
        __builtin_amdgcn_global_load_lds((gu32*)aptr[i], (lu32*)(As + wave * 2048 + i * 512), 16, 0, 0);
        aptr[i] += BK;
      }
    } else {
#pragma unroll
      for (int i = 0; i < 4; ++i) {
        float4 v0 = *(const float4*)(gptr[i]);
        float4 v1 = *(const float4*)(gptr[i] + 4);
        gptr[i] += BK;
        ushort8 o;
        o[0] = f2bf(v0.x); o[1] = f2bf(v0.y); o[2] = f2bf(v0.z); o[3] = f2bf(v0.w);
        o[4] = f2bf(v1.x); o[5] = f2bf(v1.y); o[6] = f2bf(v1.z); o[7] = f2bf(v1.w);
        int rl = wave * 32 + i * 8 + srow;
        *(ushort8*)(As + rl * 64 + seg * 8) = o;  // swizzled ds_write_b128
      }
    }
    __syncthreads();

#pragma unroll
    for (int kk = 0; kk < 2; ++kk) {
      bf16x8 af[4], bfr[4];
#pragma unroll
      for (int i = 0; i < 4; ++i) {
        int ra = w_m * 64 + i * 16 + l16;
        int rb = w_n * 64 + i * 16 + l16;
        int ps = ((kk * 4 + q) ^ (l16 & 7)) * 8;  // swizzled segment read
        af[i] = *(const bf16x8*)(As + ra * 64 + ps);
        bfr[i] = *(const bf16x8*)(Bs + rb * 64 + ps);
      }
#pragma unroll
      for (int mi = 0; mi < 4; ++mi)
#pragma unroll
        for (int ni = 0; ni < 4; ++ni)
          acc[mi][ni] = __builtin_amdgcn_mfma_f32_16x16x32_bf16(af[mi], bfr[ni], acc[mi][ni], 0, 0, 0);
    }
    __syncthreads();
  }

  float bval[4];
#pragma unroll
  for (int ni = 0; ni < 4; ++ni)
    bval[ni] = bias[(size_t)head * NTOT + n0 + w_n * 64 + ni * 16 + l16];

#pragma unroll
  for (int mi = 0; mi < 4; ++mi) {
#pragma unroll
    for (int r = 0; r < 4; ++r) {
      int m = w_m * 64 + mi * 16 + q * 4 + r;
      if (m < rows) {
        int p = row0 + m;
        if (EPI == 0) {
#pragma unroll
          for (int ni = 0; ni < 4; ++ni) {
            int n = n0 + w_n * 64 + ni * 16 + l16;
            float v = acc[mi][ni][r] + bval[ni];
            v = v > 0.f ? v : 0.f;
            Hout[(size_t)p * NTOT + n] = f2bf(v);
          }
        } else {
          int rg = order[p];
#pragma unroll
          for (int ni = 0; ni < 4; ++ni) {
            int n = n0 + w_n * 64 + ni * 16 + l16;
            Out[(size_t)rg * NTOT + n] = acc[mi][ni][r] + bval[ni];
          }
        }
      }
    }
  }
}

extern "C" void kernel_launch(void* const* d_in, const int* in_sizes, int n_in,
                              void* d_out, int out_size, void* d_ws, size_t ws_size,
                              hipStream_t stream) {
  const float* X = (const float*)d_in[0];
  const int* idxh = (const int*)d_in[1];
  const float* W1 = (const float*)d_in[2];
  const float* b1 = (const float*)d_in[3];
  const float* W2 = (const float*)d_in[4];
  const float* b2 = (const float*)d_in[5];
  float* out = (float*)d_out;

  char* ws = (char*)d_ws;
  int* order = (int*)ws;                     ws += (size_t)BATCH * 4;
  int* offsets = (int*)ws;                   ws += 64;
  unsigned short* W1t = (unsigned short*)ws; ws += (size_t)N_HEADS * IN_F * HID * 2;
  unsigned short* W2t = (unsigned short*)ws; ws += (size_t)N_HEADS * HID * OUT_F * 2;
  unsigned short* Hb = (unsigned short*)ws;  ws += (size_t)BATCH * HID * 2;

  prep_kernel<<<dim3(2305), dim3(256), 0, stream>>>(idxh, order, offsets, W1, W1t, W2, W2t);

  constexpr int MT = BATCH / 128 + N_HEADS;
  gemm_kernel<IN_F, HID, 0, 1><<<dim3(HID / 128, MT), dim3(256), 0, stream>>>(
      nullptr, X, W1t, b1, offsets, order, Hb, nullptr);
  gemm_kernel<HID, OUT_F, 1, 0><<<dim3(OUT_F / 128, MT), dim3(256), 0, stream>>>(
      Hb, nullptr, W2t, b2, offsets, order, nullptr, out);
}

// Round 2
// 138.833 us; speedup vs baseline: 1.0127x; 1.0127x over previous
//
#include <hip/hip_runtime.h>

#define IN_F 256
#define HID 512
#define OUT_F 2048
#define N_HEADS 8
#define BATCH 4096

typedef __bf16 bf16_t;
typedef bf16_t bf16x8 __attribute__((ext_vector_type(8)));
typedef float f32x4 __attribute__((ext_vector_type(4)));
typedef unsigned short ushort8 __attribute__((ext_vector_type(8)));

typedef __attribute__((address_space(1))) const unsigned int gu32;
typedef __attribute__((address_space(3))) unsigned int lu32;

__device__ inline unsigned short f2bf(float f) {
  union { float f; unsigned u; } v; v.f = f;
  unsigned u = v.u;
  unsigned r = (u + 0x7FFFu + ((u >> 16) & 1u)) >> 16;  // RNE
  return (unsigned short)r;
}

// ---------------- W transpose 64x64 tile (fp32 [K][N] -> bf16 [N][K]) ----------
// read pass: scalar fp32, coalesced. write pass: ushort4 stores (512B/wave),
// LDS reads tile[c4*4+j][rr] stride-65 rows -> bank = 4*c4+j+rr, 2 lanes/bank.
__device__ inline void transpose64(const float* __restrict__ W,
                                   unsigned short* __restrict__ Wt,
                                   int K, int N, int b, int nt, int kt,
                                   float (*tile)[65]) {
  int per_head = nt * kt;
  int h = b / per_head;
  int rem = b % per_head;
  int n0 = (rem % nt) * 64;
  int k0 = (rem / nt) * 64;
  const float* Wh = W + (size_t)h * K * N;
  unsigned short* Wth = Wt + (size_t)h * K * N;
  int c = threadIdx.x & 63;
  int r0 = threadIdx.x >> 6;  // 0..3
#pragma unroll
  for (int rr = r0; rr < 64; rr += 4)
    tile[rr][c] = Wh[(size_t)(k0 + rr) * N + n0 + c];
  __syncthreads();
  int c4 = threadIdx.x & 15;
  int r1 = threadIdx.x >> 4;  // 0..15
#pragma unroll
  for (int rr = r1; rr < 64; rr += 16) {
    ushort4 o;
    o.x = f2bf(tile[c4 * 4 + 0][rr]);
    o.y = f2bf(tile[c4 * 4 + 1][rr]);
    o.z = f2bf(tile[c4 * 4 + 2][rr]);
    o.w = f2bf(tile[c4 * 4 + 3][rr]);
    *(ushort4*)&Wth[(size_t)(n0 + rr) * K + k0 + c4 * 4] = o;
  }
}

// ---------------- K1: bucket (block 0) + W1 transpose (blocks 1..256) ---------
__global__ __launch_bounds__(256) void k1_kernel(const int* __restrict__ idx,
                                                 int* __restrict__ order,
                                                 int* __restrict__ offsets,
                                                 const float* __restrict__ W1,
                                                 unsigned short* __restrict__ W1t) {
  __shared__ float tile[64][65];
  __shared__ int cnt[N_HEADS];
  __shared__ int base[N_HEADS + 1];
  __shared__ int cur[N_HEADS];
  int b = blockIdx.x;
  if (b == 0) {
    int tid = threadIdx.x;
    if (tid < N_HEADS) cnt[tid] = 0;
    __syncthreads();
    const int4* idx4 = (const int4*)idx;
    int4 v[4];
#pragma unroll
    for (int i = 0; i < 4; ++i) v[i] = idx4[tid + i * 256];
#pragma unroll
    for (int i = 0; i < 4; ++i) {
      atomicAdd(&cnt[v[i].x], 1); atomicAdd(&cnt[v[i].y], 1);
      atomicAdd(&cnt[v[i].z], 1); atomicAdd(&cnt[v[i].w], 1);
    }
    __syncthreads();
    if (tid == 0) {
      int acc = 0;
      for (int h = 0; h < N_HEADS; ++h) { base[h] = acc; cur[h] = acc; acc += cnt[h]; }
      base[N_HEADS] = acc;
    }
    __syncthreads();
    if (tid < N_HEADS + 1) offsets[tid] = base[tid];
#pragma unroll
    for (int i = 0; i < 4; ++i) {
      int i0 = (tid + i * 256) * 4;
      order[atomicAdd(&cur[v[i].x], 1)] = i0;
      order[atomicAdd(&cur[v[i].y], 1)] = i0 + 1;
      order[atomicAdd(&cur[v[i].z], 1)] = i0 + 2;
      order[atomicAdd(&cur[v[i].w], 1)] = i0 + 3;
    }
  } else {
    transpose64(W1, W1t, IN_F, HID, b - 1, HID / 64, IN_F / 64, tile);
  }
}

// ---------------- common head-tile resolve --------------------------------
__device__ inline bool resolve_head(const int* __restrict__ offsets, int my,
                                    int& head, int& row0, int& rows) {
  head = -1; row0 = 0; rows = 0;
  int acc_t = 0;
#pragma unroll
  for (int h = 0; h < N_HEADS; ++h) {
    int o0 = offsets[h], o1 = offsets[h + 1];
    int cnt = o1 - o0;
    int t = (cnt + 127) / 128;
    if (head < 0 && my < acc_t + t) {
      head = h;
      int lt = my - acc_t;
      row0 = o0 + lt * 128;
      rows = min(128, cnt - lt * 128);
    }
    acc_t += t;
  }
  return head >= 0;
}

// ---------------- gemm1 body: 128x128, BK=64, A gathered from fp32 X ---------
// B staged via global_load_lds with inverse-swizzled source segment; A reg-
// gathered (order[]), cvt->bf16, swizzled ds_write. Single LDS buffer (hidden
// under co-resident W2-transpose blocks). Epilogue: bf16(relu(acc+bias)).
__device__ void gemm1_body(const float* __restrict__ Xf,
                           const unsigned short* __restrict__ Wt,
                           const float* __restrict__ bias,
                           const int* __restrict__ offsets,
                           const int* __restrict__ order,
                           unsigned short* __restrict__ Hout,
                           unsigned short* As, unsigned short* Bs,
                           int bx, int my) {
  constexpr int K = IN_F, NTOT = HID, BK = 64, NT = K / BK;
  int head, row0, rows;
  if (!resolve_head(offsets, my, head, row0, rows)) return;
  int n0 = bx * 128;
  const unsigned short* Bh = Wt + (size_t)head * (size_t)NTOT * K;

  int tid = threadIdx.x;
  int wave = tid >> 6;
  int lane = tid & 63;
  int q = lane >> 4;
  int l16 = lane & 15;
  int w_m = wave >> 1, w_n = wave & 1;

  int srow = lane >> 3;
  int seg = lane & 7;
  int segl = seg ^ srow;

  const unsigned short* bptr[4];
  const float* gptr[4];
#pragma unroll
  for (int i = 0; i < 4; ++i) {
    int rl = wave * 32 + i * 8 + srow;
    bptr[i] = Bh + (size_t)(n0 + rl) * K + segl * 8;
    int pr = row0 + min(rl, rows - 1);
    gptr[i] = Xf + (size_t)order[pr] * K + segl * 8;
  }

  f32x4 acc[4][4];
#pragma unroll
  for (int i = 0; i < 4; ++i)
#pragma unroll
    for (int j = 0; j < 4; ++j) acc[i][j] = (f32x4){0.f, 0.f, 0.f, 0.f};

#pragma unroll
  for (int t = 0; t < NT; ++t) {
#pragma unroll
    for (int i = 0; i < 4; ++i) {
      __builtin_amdgcn_global_load_lds((gu32*)bptr[i], (lu32*)(Bs + wave * 2048 + i * 512), 16, 0, 0);
      bptr[i] += BK;
    }
#pragma unroll
    for (int i = 0; i < 4; ++i) {
      float4 v0 = *(const float4*)(gptr[i]);
      float4 v1 = *(const float4*)(gptr[i] + 4);
      gptr[i] += BK;
      ushort8 o;
      o[0] = f2bf(v0.x); o[1] = f2bf(v0.y); o[2] = f2bf(v0.z); o[3] = f2bf(v0.w);
      o[4] = f2bf(v1.x); o[5] = f2bf(v1.y); o[6] = f2bf(v1.z); o[7] = f2bf(v1.w);
      int rl = wave * 32 + i * 8 + srow;
      *(ushort8*)(As + rl * 64 + seg * 8) = o;
    }
    __syncthreads();
#pragma unroll
    for (int kk = 0; kk < 2; ++kk) {
      bf16x8 af[4], bfr[4];
#pragma unroll
      for (int i = 0; i < 4; ++i) {
        int ps = ((kk * 4 + q) ^ (l16 & 7)) * 8;
        af[i] = *(const bf16x8*)(As + (w_m * 64 + i * 16 + l16) * 64 + ps);
        bfr[i] = *(const bf16x8*)(Bs + (w_n * 64 + i * 16 + l16) * 64 + ps);
      }
#pragma unroll
      for (int mi = 0; mi < 4; ++mi)
#pragma unroll
        for (int ni = 0; ni < 4; ++ni)
          acc[mi][ni] = __builtin_amdgcn_mfma_f32_16x16x32_bf16(af[mi], bfr[ni], acc[mi][ni], 0, 0, 0);
    }
    __syncthreads();
  }

  float bval[4];
#pragma unroll
  for (int ni = 0; ni < 4; ++ni)
    bval[ni] = bias[(size_t)head * NTOT + n0 + w_n * 64 + ni * 16 + l16];

#pragma unroll
  for (int mi = 0; mi < 4; ++mi) {
#pragma unroll
    for (int r = 0; r < 4; ++r) {
      int m = w_m * 64 + mi * 16 + q * 4 + r;
      if (m < rows) {
        int p = row0 + m;
#pragma unroll
        for (int ni = 0; ni < 4; ++ni) {
          int n = n0 + w_n * 64 + ni * 16 + l16;
          float v = acc[mi][ni][r] + bval[ni];
          v = v > 0.f ? v : 0.f;
          Hout[(size_t)p * NTOT + n] = f2bf(v);
        }
      }
    }
  }
}

// ---------------- K2: gemm1 (blocks 0..159) || W2 transpose (160..2207) ------
__global__ __launch_bounds__(256) void k2_kernel(const float* __restrict__ X,
                                                 const int* __restrict__ order,
                                                 const int* __restrict__ offsets,
                                                 const unsigned short* __restrict__ W1t,
                                                 const float* __restrict__ b1,
                                                 unsigned short* __restrict__ Hb,
                                                 const float* __restrict__ W2,
                                                 unsigned short* __restrict__ W2t) {
  __shared__ __align__(16) unsigned char smem[32768];
  int b = blockIdx.x;
  if (b < 160) {
    gemm1_body(X, W1t, b1, offsets, order, Hb,
               (unsigned short*)smem, (unsigned short*)(smem + 16384),
               b & 3, b >> 2);
  } else {
    transpose64(W2, W2t, HID, OUT_F, b - 160, OUT_F / 64, HID / 64,
                (float(*)[65])smem);
  }
}

// ---------------- K3: gemm2, 128x128, BK=64, double-buffered 2-phase ---------
// stage(t+1) issued BEFORE compute(t); single __syncthreads per iter does the
// vmcnt drain after MFMA+ds_read covered the load latency (T3-minimum recipe).
__global__ __launch_bounds__(256) void gemm2_kernel(const unsigned short* __restrict__ A,
                                                    const unsigned short* __restrict__ Wt,
                                                    const float* __restrict__ bias,
                                                    const int* __restrict__ offsets,
                                                    const int* __restrict__ order,
                                                    float* __restrict__ Out) {
  constexpr int K = HID, NTOT = OUT_F, BK = 64, NT = K / BK;  // NT = 8
  __shared__ __align__(16) unsigned short As[2][128 * BK];
  __shared__ __align__(16) unsigned short Bs[2][128 * BK];

  int head, row0, rows;
  if (!resolve_head(offsets, blockIdx.y, head, row0, rows)) return;
  int n0 = blockIdx.x * 128;
  const unsigned short* Bh = Wt + (size_t)head * (size_t)NTOT * K;

  int tid = threadIdx.x;
  int wave = tid >> 6;
  int lane = tid & 63;
  int q = lane >> 4;
  int l16 = lane & 15;
  int w_m = wave >> 1, w_n = wave & 1;

  int srow = lane >> 3;
  int seg = lane & 7;
  int segl = seg ^ srow;

  const unsigned short* aptr[4];
  const unsigned short* bptr[4];
#pragma unroll
  for (int i = 0; i < 4; ++i) {
    int rl = wave * 32 + i * 8 + srow;
    bptr[i] = Bh + (size_t)(n0 + rl) * K + segl * 8;
    int pr = row0 + min(rl, rows - 1);
    aptr[i] = A + (size_t)pr * K + segl * 8;
  }

  f32x4 acc[4][4];
#pragma unroll
  for (int i = 0; i < 4; ++i)
#pragma unroll
    for (int j = 0; j < 4; ++j) acc[i][j] = (f32x4){0.f, 0.f, 0.f, 0.f};

  // prologue: stage tile 0 into buffer 0
#pragma unroll
  for (int i = 0; i < 4; ++i) {
    __builtin_amdgcn_global_load_lds((gu32*)bptr[i], (lu32*)(&Bs[0][wave * 2048 + i * 512]), 16, 0, 0);
    bptr[i] += BK;
    __builtin_amdgcn_global_load_lds((gu32*)aptr[i], (lu32*)(&As[0][wave * 2048 + i * 512]), 16, 0, 0);
    aptr[i] += BK;
  }
  __syncthreads();

  int cur = 0;
#pragma unroll
  for (int t = 0; t < NT; ++t) {
    if (t + 1 < NT) {
#pragma unroll
      for (int i = 0; i < 4; ++i) {
        __builtin_amdgcn_global_load_lds((gu32*)bptr[i], (lu32*)(&Bs[cur ^ 1][wave * 2048 + i * 512]), 16, 0, 0);
        bptr[i] += BK;
        __builtin_amdgcn_global_load_lds((gu32*)aptr[i], (lu32*)(&As[cur ^ 1][wave * 2048 + i * 512]), 16, 0, 0);
        aptr[i] += BK;
      }
    }
#pragma unroll
    for (int kk = 0; kk < 2; ++kk) {
      bf16x8 af[4], bfr[4];
#pragma unroll
      for (int i = 0; i < 4; ++i) {
        int ps = ((kk * 4 + q) ^ (l16 & 7)) * 8;
        af[i] = *(const bf16x8*)(&As[cur][(w_m * 64 + i * 16 + l16) * 64 + ps]);
        bfr[i] = *(const bf16x8*)(&Bs[cur][(w_n * 64 + i * 16 + l16) * 64 + ps]);
      }
#pragma unroll
      for (int mi = 0; mi < 4; ++mi)
#pragma unroll
        for (int ni = 0; ni < 4; ++ni)
          acc[mi][ni] = __builtin_amdgcn_mfma_f32_16x16x32_bf16(af[mi], bfr[ni], acc[mi][ni], 0, 0, 0);
    }
    __syncthreads();  // drains vmcnt (stage t+1) + joins; buf cur^1 now ready
    cur ^= 1;
  }

  float bval[4];
#pragma unroll
  for (int ni = 0; ni < 4; ++ni)
    bval[ni] = bias[(size_t)head * NTOT + n0 + w_n * 64 + ni * 16 + l16];

#pragma unroll
  for (int mi = 0; mi < 4; ++mi) {
#pragma unroll
    for (int r = 0; r < 4; ++r) {
      int m = w_m * 64 + mi * 16 + q * 4 + r;
      if (m < rows) {
        int rg = order[row0 + m];
#pragma unroll
        for (int ni = 0; ni < 4; ++ni) {
          int n = n0 + w_n * 64 + ni * 16 + l16;
          Out[(size_t)rg * NTOT + n] = acc[mi][ni][r] + bval[ni];
        }
      }
    }
  }
}

extern "C" void kernel_launch(void* const* d_in, const int* in_sizes, int n_in,
                              void* d_out, int out_size, void* d_ws, size_t ws_size,
                              hipStream_t stream) {
  const float* X = (const float*)d_in[0];
  const int* idxh = (const int*)d_in[1];
  const float* W1 = (const float*)d_in[2];
  const float* b1 = (const float*)d_in[3];
  const float* W2 = (const float*)d_in[4];
  const float* b2 = (const float*)d_in[5];
  float* out = (float*)d_out;

  char* ws = (char*)d_ws;
  int* order = (int*)ws;                     ws += (size_t)BATCH * 4;
  int* offsets = (int*)ws;                   ws += 64;
  unsigned short* W1t = (unsigned short*)ws; ws += (size_t)N_HEADS * IN_F * HID * 2;
  unsigned short* W2t = (unsigned short*)ws; ws += (size_t)N_HEADS * HID * OUT_F * 2;
  unsigned short* Hb = (unsigned short*)ws;  ws += (size_t)BATCH * HID * 2;

  k1_kernel<<<dim3(257), dim3(256), 0, stream>>>(idxh, order, offsets, W1, W1t);
  k2_kernel<<<dim3(2208), dim3(256), 0, stream>>>(X, order, offsets, W1t, b1, Hb, W2, W2t);

  constexpr int MT = BATCH / 128 + N_HEADS;
  gemm2_kernel<<<dim3(OUT_F / 128, MT), dim3(256), 0, stream>>>(
      Hb, W2t, b2, offsets, order, out);
}

// Round 3
// 132.582 us; speedup vs baseline: 1.0604x; 1.0472x over previous
//
#include <hip/hip_runtime.h>

#define IN_F 256
#define HID 512
#define OUT_F 2048
#define N_HEADS 8
#define BATCH 4096

typedef __bf16 bf16_t;
typedef bf16_t bf16x8 __attribute__((ext_vector_type(8)));
typedef float f32x4 __attribute__((ext_vector_type(4)));

typedef __attribute__((address_space(1))) const unsigned int gu32;
typedef __attribute__((address_space(3))) unsigned int lu32;

__device__ inline unsigned short f2bf(float f) {
  union { float f; unsigned u; } v; v.f = f;
  unsigned u = v.u;
  unsigned r = (u + 0x7FFFu + ((u >> 16) & 1u)) >> 16;  // RNE
  return (unsigned short)r;
}

// ---------------- W transpose 64x64 tile (fp32 [K][N] -> bf16 [N][K]) ----------
// pass 1: float4 global reads (1KB/wave/instr), scalar LDS writes into [65]-pad
//         tile (bank = rr + 4*c16 + j mod 32 -> 2 lanes/bank, free).
// pass 2: scalar LDS reads tile[c4*4+j][rr] (bank = 4c4+j+rr, 2 lanes/bank),
//         ushort4 global stores (512B/wave/instr).
__device__ inline void transpose64(const float* __restrict__ W,
                                   unsigned short* __restrict__ Wt,
                                   int K, int N, int b, int nt, int kt,
                                   float (*tile)[65]) {
  int per_head = nt * kt;
  int h = b / per_head;
  int rem = b % per_head;
  int n0 = (rem % nt) * 64;
  int k0 = (rem / nt) * 64;
  const float* Wh = W + (size_t)h * K * N;
  unsigned short* Wth = Wt + (size_t)h * K * N;
  int c16 = threadIdx.x & 15;
  int r16 = threadIdx.x >> 4;  // 0..15
#pragma unroll
  for (int rr = r16; rr < 64; rr += 16) {
    float4 v = *(const float4*)&Wh[(size_t)(k0 + rr) * N + n0 + c16 * 4];
    tile[rr][c16 * 4 + 0] = v.x;
    tile[rr][c16 * 4 + 1] = v.y;
    tile[rr][c16 * 4 + 2] = v.z;
    tile[rr][c16 * 4 + 3] = v.w;
  }
  __syncthreads();
  int c4 = threadIdx.x & 15;
  int r1 = threadIdx.x >> 4;
#pragma unroll
  for (int rr = r1; rr < 64; rr += 16) {
    ushort4 o;
    o.x = f2bf(tile[c4 * 4 + 0][rr]);
    o.y = f2bf(tile[c4 * 4 + 1][rr]);
    o.z = f2bf(tile[c4 * 4 + 2][rr]);
    o.w = f2bf(tile[c4 * 4 + 3][rr]);
    *(ushort4*)&Wth[(size_t)(n0 + rr) * K + k0 + c4 * 4] = o;
  }
}

// ---- K1: bucket (blk 0) | X fp32->bf16 convert (blks 1..128) | W1t (129..384)
__global__ __launch_bounds__(256) void k1_kernel(const int* __restrict__ idx,
                                                 const float* __restrict__ X,
                                                 unsigned short* __restrict__ Xb,
                                                 int* __restrict__ order,
                                                 int* __restrict__ offsets,
                                                 const float* __restrict__ W1,
                                                 unsigned short* __restrict__ W1t) {
  __shared__ float tile[64][65];
  __shared__ int cnt[N_HEADS];
  __shared__ int base[N_HEADS + 1];
  __shared__ int cur[N_HEADS];
  int b = blockIdx.x;
  int tid = threadIdx.x;
  if (b == 0) {
    if (tid < N_HEADS) cnt[tid] = 0;
    __syncthreads();
    const int4* idx4 = (const int4*)idx;
    int4 v[4];
#pragma unroll
    for (int i = 0; i < 4; ++i) v[i] = idx4[tid + i * 256];
#pragma unroll
    for (int i = 0; i < 4; ++i) {
      atomicAdd(&cnt[v[i].x], 1); atomicAdd(&cnt[v[i].y], 1);
      atomicAdd(&cnt[v[i].z], 1); atomicAdd(&cnt[v[i].w], 1);
    }
    __syncthreads();
    if (tid == 0) {
      int acc = 0;
      for (int h = 0; h < N_HEADS; ++h) { base[h] = acc; cur[h] = acc; acc += cnt[h]; }
      base[N_HEADS] = acc;
    }
    __syncthreads();
    if (tid < N_HEADS + 1) offsets[tid] = base[tid];
#pragma unroll
    for (int i = 0; i < 4; ++i) {
      int i0 = (tid + i * 256) * 4;
      order[atomicAdd(&cur[v[i].x], 1)] = i0;
      order[atomicAdd(&cur[v[i].y], 1)] = i0 + 1;
      order[atomicAdd(&cur[v[i].z], 1)] = i0 + 2;
      order[atomicAdd(&cur[v[i].w], 1)] = i0 + 3;
    }
  } else if (b < 129) {
    // convert 2048 float4 per block: (BATCH*IN_F/4) / 128 blocks
    const float4* X4 = (const float4*)X;
    ushort4* O4 = (ushort4*)Xb;
    int base_i = (b - 1) * 2048 + tid;
#pragma unroll
    for (int it = 0; it < 8; ++it) {
      float4 v = X4[base_i + it * 256];
      ushort4 o;
      o.x = f2bf(v.x); o.y = f2bf(v.y); o.z = f2bf(v.z); o.w = f2bf(v.w);
      O4[base_i + it * 256] = o;
    }
  } else {
    transpose64(W1, W1t, IN_F, HID, b - 129, HID / 64, IN_F / 64, tile);
  }
}

// ---------------- common head-tile resolve --------------------------------
__device__ inline bool resolve_head(const int* __restrict__ offsets, int my,
                                    int& head, int& row0, int& rows) {
  head = -1; row0 = 0; rows = 0;
  int acc_t = 0;
#pragma unroll
  for (int h = 0; h < N_HEADS; ++h) {
    int o0 = offsets[h], o1 = offsets[h + 1];
    int cnt = o1 - o0;
    int t = (cnt + 127) / 128;
    if (head < 0 && my < acc_t + t) {
      head = h;
      int lt = my - acc_t;
      row0 = o0 + lt * 128;
      rows = min(128, cnt - lt * 128);
    }
    acc_t += t;
  }
  return head >= 0;
}

// ---- gemm1 body: 128x128, BK=64; A = bf16 Xb rows gathered via order[] with
// per-lane-source global_load_lds (dest linear, source segment pre-swizzled).
// Single LDS buffer (32KB) so co-resident W2-transpose blocks keep occupancy.
__device__ void gemm1_body(const unsigned short* __restrict__ Xb,
                           const unsigned short* __restrict__ Wt,
                           const float* __restrict__ bias,
                           const int* __restrict__ offsets,
                           const int* __restrict__ order,
                           unsigned short* __restrict__ Hout,
                           unsigned short* As, unsigned short* Bs,
                           int bx, int my) {
  constexpr int K = IN_F, NTOT = HID, BK = 64, NT = K / BK;  // NT=4
  int head, row0, rows;
  if (!resolve_head(offsets, my, head, row0, rows)) return;
  int n0 = bx * 128;
  const unsigned short* Bh = Wt + (size_t)head * (size_t)NTOT * K;

  int tid = threadIdx.x;
  int wave = tid >> 6;
  int lane = tid & 63;
  int q = lane >> 4;
  int l16 = lane & 15;
  int w_m = wave >> 1, w_n = wave & 1;

  int srow = lane >> 3;
  int seg = lane & 7;
  int segl = seg ^ srow;

  const unsigned short* aptr[4];
  const unsigned short* bptr[4];
#pragma unroll
  for (int i = 0; i < 4; ++i) {
    int rl = wave * 32 + i * 8 + srow;
    bptr[i] = Bh + (size_t)(n0 + rl) * K + segl * 8;
    int pr = row0 + min(rl, rows - 1);
    aptr[i] = Xb + (size_t)order[pr] * K + segl * 8;
  }

  f32x4 acc[4][4];
#pragma unroll
  for (int i = 0; i < 4; ++i)
#pragma unroll
    for (int j = 0; j < 4; ++j) acc[i][j] = (f32x4){0.f, 0.f, 0.f, 0.f};

#pragma unroll
  for (int t = 0; t < NT; ++t) {
#pragma unroll
    for (int i = 0; i < 4; ++i) {
      __builtin_amdgcn_global_load_lds((gu32*)bptr[i], (lu32*)(Bs + wave * 2048 + i * 512), 16, 0, 0);
      bptr[i] += BK;
      __builtin_amdgcn_global_load_lds((gu32*)aptr[i], (lu32*)(As + wave * 2048 + i * 512), 16, 0, 0);
      aptr[i] += BK;
    }
    __syncthreads();
#pragma unroll
    for (int kk = 0; kk < 2; ++kk) {
      bf16x8 af[4], bfr[4];
#pragma unroll
      for (int i = 0; i < 4; ++i) {
        int ps = ((kk * 4 + q) ^ (l16 & 7)) * 8;
        af[i] = *(const bf16x8*)(As + (w_m * 64 + i * 16 + l16) * 64 + ps);
        bfr[i] = *(const bf16x8*)(Bs + (w_n * 64 + i * 16 + l16) * 64 + ps);
      }
#pragma unroll
      for (int mi = 0; mi < 4; ++mi)
#pragma unroll
        for (int ni = 0; ni < 4; ++ni)
          acc[mi][ni] = __builtin_amdgcn_mfma_f32_16x16x32_bf16(af[mi], bfr[ni], acc[mi][ni], 0, 0, 0);
    }
    __syncthreads();
  }

  float bval[4];
#pragma unroll
  for (int ni = 0; ni < 4; ++ni)
    bval[ni] = bias[(size_t)head * NTOT + n0 + w_n * 64 + ni * 16 + l16];

#pragma unroll
  for (int mi = 0; mi < 4; ++mi) {
#pragma unroll
    for (int r = 0; r < 4; ++r) {
      int m = w_m * 64 + mi * 16 + q * 4 + r;
      if (m < rows) {
        int p = row0 + m;
#pragma unroll
        for (int ni = 0; ni < 4; ++ni) {
          int n = n0 + w_n * 64 + ni * 16 + l16;
          float v = acc[mi][ni][r] + bval[ni];
          v = v > 0.f ? v : 0.f;
          Hout[(size_t)p * NTOT + n] = f2bf(v);
        }
      }
    }
  }
}

// ---------------- K2: gemm1 (blocks 0..159) || W2 transpose (160..2207) ------
__global__ __launch_bounds__(256) void k2_kernel(const unsigned short* __restrict__ Xb,
                                                 const int* __restrict__ order,
                                                 const int* __restrict__ offsets,
                                                 const unsigned short* __restrict__ W1t,
                                                 const float* __restrict__ b1,
                                                 unsigned short* __restrict__ Hb,
                                                 const float* __restrict__ W2,
                                                 unsigned short* __restrict__ W2t) {
  __shared__ __align__(16) unsigned char smem[32768];
  int b = blockIdx.x;
  if (b < 160) {
    gemm1_body(Xb, W1t, b1, offsets, order, Hb,
               (unsigned short*)smem, (unsigned short*)(smem + 16384),
               b & 3, b >> 2);
  } else {
    transpose64(W2, W2t, HID, OUT_F, b - 160, OUT_F / 64, HID / 64,
                (float(*)[65])smem);
  }
}

// ---------------- K3: gemm2, 128x128, BK=64, double-buffered 2-phase ---------
// stage(t+1) issued BEFORE compute(t); single __syncthreads per iter does the
// vmcnt drain after MFMA+ds_read covered the load latency (T3-minimum recipe).
__global__ __launch_bounds__(256) void gemm2_kernel(const unsigned short* __restrict__ A,
                                                    const unsigned short* __restrict__ Wt,
                                                    const float* __restrict__ bias,
                                                    const int* __restrict__ offsets,
                                                    const int* __restrict__ order,
                                                    float* __restrict__ Out) {
  constexpr int K = HID, NTOT = OUT_F, BK = 64, NT = K / BK;  // NT = 8
  __shared__ __align__(16) unsigned short As[2][128 * BK];
  __shared__ __align__(16) unsigned short Bs[2][128 * BK];

  int head, row0, rows;
  if (!resolve_head(offsets, blockIdx.y, head, row0, rows)) return;
  int n0 = blockIdx.x * 128;
  const unsigned short* Bh = Wt + (size_t)head * (size_t)NTOT * K;

  int tid = threadIdx.x;
  int wave = tid >> 6;
  int lane = tid & 63;
  int q = lane >> 4;
  int l16 = lane & 15;
  int w_m = wave >> 1, w_n = wave & 1;

  int srow = lane >> 3;
  int seg = lane & 7;
  int segl = seg ^ srow;

  const unsigned short* aptr[4];
  const unsigned short* bptr[4];
#pragma unroll
  for (int i = 0; i < 4; ++i) {
    int rl = wave * 32 + i * 8 + srow;
    bptr[i] = Bh + (size_t)(n0 + rl) * K + segl * 8;
    int pr = row0 + min(rl, rows - 1);
    aptr[i] = A + (size_t)pr * K + segl * 8;
  }

  f32x4 acc[4][4];
#pragma unroll
  for (int i = 0; i < 4; ++i)
#pragma unroll
    for (int j = 0; j < 4; ++j) acc[i][j] = (f32x4){0.f, 0.f, 0.f, 0.f};

  // prologue: stage tile 0 into buffer 0
#pragma unroll
  for (int i = 0; i < 4; ++i) {
    __builtin_amdgcn_global_load_lds((gu32*)bptr[i], (lu32*)(&Bs[0][wave * 2048 + i * 512]), 16, 0, 0);
    bptr[i] += BK;
    __builtin_amdgcn_global_load_lds((gu32*)aptr[i], (lu32*)(&As[0][wave * 2048 + i * 512]), 16, 0, 0);
    aptr[i] += BK;
  }
  __syncthreads();

  int cur = 0;
#pragma unroll
  for (int t = 0; t < NT; ++t) {
    if (t + 1 < NT) {
#pragma unroll
      for (int i = 0; i < 4; ++i) {
        __builtin_amdgcn_global_load_lds((gu32*)bptr[i], (lu32*)(&Bs[cur ^ 1][wave * 2048 + i * 512]), 16, 0, 0);
        bptr[i] += BK;
        __builtin_amdgcn_global_load_lds((gu32*)aptr[i], (lu32*)(&As[cur ^ 1][wave * 2048 + i * 512]), 16, 0, 0);
        aptr[i] += BK;
      }
    }
#pragma unroll
    for (int kk = 0; kk < 2; ++kk) {
      bf16x8 af[4], bfr[4];
#pragma unroll
      for (int i = 0; i < 4; ++i) {
        int ps = ((kk * 4 + q) ^ (l16 & 7)) * 8;
        af[i] = *(const bf16x8*)(&As[cur][(w_m * 64 + i * 16 + l16) * 64 + ps]);
        bfr[i] = *(const bf16x8*)(&Bs[cur][(w_n * 64 + i * 16 + l16) * 64 + ps]);
      }
#pragma unroll
      for (int mi = 0; mi < 4; ++mi)
#pragma unroll
        for (int ni = 0; ni < 4; ++ni)
          acc[mi][ni] = __builtin_amdgcn_mfma_f32_16x16x32_bf16(af[mi], bfr[ni], acc[mi][ni], 0, 0, 0);
    }
    __syncthreads();  // drains vmcnt (stage t+1) + joins; buf cur^1 now ready
    cur ^= 1;
  }

  float bval[4];
#pragma unroll
  for (int ni = 0; ni < 4; ++ni)
    bval[ni] = bias[(size_t)head * NTOT + n0 + w_n * 64 + ni * 16 + l16];

#pragma unroll
  for (int mi = 0; mi < 4; ++mi) {
#pragma unroll
    for (int r = 0; r < 4; ++r) {
      int m = w_m * 64 + mi * 16 + q * 4 + r;
      if (m < rows) {
        int rg = order[row0 + m];
#pragma unroll
        for (int ni = 0; ni < 4; ++ni) {
          int n = n0 + w_n * 64 + ni * 16 + l16;
          Out[(size_t)rg * NTOT + n] = acc[mi][ni][r] + bval[ni];
        }
      }
    }
  }
}

extern "C" void kernel_launch(void* const* d_in, const int* in_sizes, int n_in,
                              void* d_out, int out_size, void* d_ws, size_t ws_size,
                              hipStream_t stream) {
  const float* X = (const float*)d_in[0];
  const int* idxh = (const int*)d_in[1];
  const float* W1 = (const float*)d_in[2];
  const float* b1 = (const float*)d_in[3];
  const float* W2 = (const float*)d_in[4];
  const float* b2 = (const float*)d_in[5];
  float* out = (float*)d_out;

  char* ws = (char*)d_ws;
  int* order = (int*)ws;                     ws += (size_t)BATCH * 4;
  int* offsets = (int*)ws;                   ws += 64;
  unsigned short* Xb = (unsigned short*)ws;  ws += (size_t)BATCH * IN_F * 2;
  unsigned short* W1t = (unsigned short*)ws; ws += (size_t)N_HEADS * IN_F * HID * 2;
  unsigned short* W2t = (unsigned short*)ws; ws += (size_t)N_HEADS * HID * OUT_F * 2;
  unsigned short* Hb = (unsigned short*)ws;  ws += (size_t)BATCH * HID * 2;

  k1_kernel<<<dim3(385), dim3(256), 0, stream>>>(idxh, X, Xb, order, offsets, W1, W1t);
  k2_kernel<<<dim3(2208), dim3(256), 0, stream>>>(Xb, order, offsets, W1t, b1, Hb, W2, W2t);

  constexpr int MT = BATCH / 128 + N_HEADS;
  gemm2_kernel<<<dim3(OUT_F / 128, MT), dim3(256), 0, stream>>>(
      Hb, W2t, b2, offsets, order, out);
}

// Round 4
// 130.893 us; speedup vs baseline: 1.0741x; 1.0129x over previous
//
#include <hip/hip_runtime.h>

#define IN_F 256
#define HID 512
#define OUT_F 2048
#define N_HEADS 8
#define BATCH 4096

typedef __bf16 bf16_t;
typedef bf16_t bf16x8 __attribute__((ext_vector_type(8)));
typedef float f32x4 __attribute__((ext_vector_type(4)));

typedef __attribute__((address_space(1))) const unsigned int gu32;
typedef __attribute__((address_space(3))) unsigned int lu32;

__device__ inline unsigned short f2bf(float f) {
  union { float f; unsigned u; } v; v.f = f;
  unsigned u = v.u;
  unsigned r = (u + 0x7FFFu + ((u >> 16) & 1u)) >> 16;  // RNE
  return (unsigned short)r;
}

// ---------------- W transpose 64x64 tile (fp32 [K][N] -> bf16 [N][K]) ----------
// pass 1: float4 global reads (1KB/wave/instr), scalar LDS writes into [65]-pad
//         tile (2 lanes/bank, free). pass 2: scalar LDS reads (2 lanes/bank),
//         ushort4 global stores (512B/wave/instr).
__device__ inline void transpose64(const float* __restrict__ W,
                                   unsigned short* __restrict__ Wt,
                                   int K, int N, int b, int nt, int kt,
                                   float (*tile)[65]) {
  int per_head = nt * kt;
  int h = b / per_head;
  int rem = b % per_head;
  int n0 = (rem % nt) * 64;
  int k0 = (rem / nt) * 64;
  const float* Wh = W + (size_t)h * K * N;
  unsigned short* Wth = Wt + (size_t)h * K * N;
  int c16 = threadIdx.x & 15;
  int r16 = threadIdx.x >> 4;  // 0..15
#pragma unroll
  for (int rr = r16; rr < 64; rr += 16) {
    float4 v = *(const float4*)&Wh[(size_t)(k0 + rr) * N + n0 + c16 * 4];
    tile[rr][c16 * 4 + 0] = v.x;
    tile[rr][c16 * 4 + 1] = v.y;
    tile[rr][c16 * 4 + 2] = v.z;
    tile[rr][c16 * 4 + 3] = v.w;
  }
  __syncthreads();
  int c4 = threadIdx.x & 15;
  int r1 = threadIdx.x >> 4;
#pragma unroll
  for (int rr = r1; rr < 64; rr += 16) {
    ushort4 o;
    o.x = f2bf(tile[c4 * 4 + 0][rr]);
    o.y = f2bf(tile[c4 * 4 + 1][rr]);
    o.z = f2bf(tile[c4 * 4 + 2][rr]);
    o.w = f2bf(tile[c4 * 4 + 3][rr]);
    *(ushort4*)&Wth[(size_t)(n0 + rr) * K + k0 + c4 * 4] = o;
  }
}

// ---- K1: bucket (blk 0) | X fp32->bf16 convert (blks 1..128) | W1t (129..384)
__global__ __launch_bounds__(256) void k1_kernel(const int* __restrict__ idx,
                                                 const float* __restrict__ X,
                                                 unsigned short* __restrict__ Xb,
                                                 int* __restrict__ order,
                                                 int* __restrict__ offsets,
                                                 const float* __restrict__ W1,
                                                 unsigned short* __restrict__ W1t) {
  __shared__ float tile[64][65];
  __shared__ int cnt[N_HEADS];
  __shared__ int base[N_HEADS + 1];
  __shared__ int cur[N_HEADS];
  int b = blockIdx.x;
  int tid = threadIdx.x;
  if (b == 0) {
    if (tid < N_HEADS) cnt[tid] = 0;
    __syncthreads();
    const int4* idx4 = (const int4*)idx;
    int4 v[4];
#pragma unroll
    for (int i = 0; i < 4; ++i) v[i] = idx4[tid + i * 256];
#pragma unroll
    for (int i = 0; i < 4; ++i) {
      atomicAdd(&cnt[v[i].x], 1); atomicAdd(&cnt[v[i].y], 1);
      atomicAdd(&cnt[v[i].z], 1); atomicAdd(&cnt[v[i].w], 1);
    }
    __syncthreads();
    if (tid == 0) {
      int acc = 0;
      for (int h = 0; h < N_HEADS; ++h) { base[h] = acc; cur[h] = acc; acc += cnt[h]; }
      base[N_HEADS] = acc;
    }
    __syncthreads();
    if (tid < N_HEADS + 1) offsets[tid] = base[tid];
#pragma unroll
    for (int i = 0; i < 4; ++i) {
      int i0 = (tid + i * 256) * 4;
      order[atomicAdd(&cur[v[i].x], 1)] = i0;
      order[atomicAdd(&cur[v[i].y], 1)] = i0 + 1;
      order[atomicAdd(&cur[v[i].z], 1)] = i0 + 2;
      order[atomicAdd(&cur[v[i].w], 1)] = i0 + 3;
    }
  } else if (b < 129) {
    const float4* X4 = (const float4*)X;
    ushort4* O4 = (ushort4*)Xb;
    int base_i = (b - 1) * 2048 + tid;
#pragma unroll
    for (int it = 0; it < 8; ++it) {
      float4 v = X4[base_i + it * 256];
      ushort4 o;
      o.x = f2bf(v.x); o.y = f2bf(v.y); o.z = f2bf(v.z); o.w = f2bf(v.w);
      O4[base_i + it * 256] = o;
    }
  } else {
    transpose64(W1, W1t, IN_F, HID, b - 129, HID / 64, IN_F / 64, tile);
  }
}

// ---------------- common head-tile resolve --------------------------------
__device__ inline bool resolve_head(const int* __restrict__ offsets, int my,
                                    int& head, int& row0, int& rows) {
  head = -1; row0 = 0; rows = 0;
  int acc_t = 0;
#pragma unroll
  for (int h = 0; h < N_HEADS; ++h) {
    int o0 = offsets[h], o1 = offsets[h + 1];
    int cnt = o1 - o0;
    int t = (cnt + 127) / 128;
    if (head < 0 && my < acc_t + t) {
      head = h;
      int lt = my - acc_t;
      row0 = o0 + lt * 128;
      rows = min(128, cnt - lt * 128);
    }
    acc_t += t;
  }
  return head >= 0;
}

// ---- gemm1 body: 128x128, BK=64; A = bf16 Xb rows gathered via order[] with
// per-lane-source global_load_lds (dest linear, source segment pre-swizzled).
// Single LDS buffer (32KB); hidden under co-resident W2-transpose blocks.
__device__ void gemm1_body(const unsigned short* __restrict__ Xb,
                           const unsigned short* __restrict__ Wt,
                           const float* __restrict__ bias,
                           const int* __restrict__ offsets,
                           const int* __restrict__ order,
                           unsigned short* __restrict__ Hout,
                           unsigned short* As, unsigned short* Bs,
                           int bx, int my) {
  constexpr int K = IN_F, NTOT = HID, BK = 64, NT = K / BK;  // NT=4
  int head, row0, rows;
  if (!resolve_head(offsets, my, head, row0, rows)) return;
  int n0 = bx * 128;
  const unsigned short* Bh = Wt + (size_t)head * (size_t)NTOT * K;

  int tid = threadIdx.x;
  int wave = tid >> 6;
  int lane = tid & 63;
  int q = lane >> 4;
  int l16 = lane & 15;
  int w_m = wave >> 1, w_n = wave & 1;

  int srow = lane >> 3;
  int seg = lane & 7;
  int segl = seg ^ srow;

  const unsigned short* aptr[4];
  const unsigned short* bptr[4];
#pragma unroll
  for (int i = 0; i < 4; ++i) {
    int rl = wave * 32 + i * 8 + srow;
    bptr[i] = Bh + (size_t)(n0 + rl) * K + segl * 8;
    int pr = row0 + min(rl, rows - 1);
    aptr[i] = Xb + (size_t)order[pr] * K + segl * 8;
  }

  f32x4 acc[4][4];
#pragma unroll
  for (int i = 0; i < 4; ++i)
#pragma unroll
    for (int j = 0; j < 4; ++j) acc[i][j] = (f32x4){0.f, 0.f, 0.f, 0.f};

#pragma unroll
  for (int t = 0; t < NT; ++t) {
#pragma unroll
    for (int i = 0; i < 4; ++i) {
      __builtin_amdgcn_global_load_lds((gu32*)bptr[i], (lu32*)(Bs + wave * 2048 + i * 512), 16, 0, 0);
      bptr[i] += BK;
      __builtin_amdgcn_global_load_lds((gu32*)aptr[i], (lu32*)(As + wave * 2048 + i * 512), 16, 0, 0);
      aptr[i] += BK;
    }
    __syncthreads();
#pragma unroll
    for (int kk = 0; kk < 2; ++kk) {
      bf16x8 af[4], bfr[4];
#pragma unroll
      for (int i = 0; i < 4; ++i) {
        int ps = ((kk * 4 + q) ^ (l16 & 7)) * 8;
        af[i] = *(const bf16x8*)(As + (w_m * 64 + i * 16 + l16) * 64 + ps);
        bfr[i] = *(const bf16x8*)(Bs + (w_n * 64 + i * 16 + l16) * 64 + ps);
      }
#pragma unroll
      for (int mi = 0; mi < 4; ++mi)
#pragma unroll
        for (int ni = 0; ni < 4; ++ni)
          acc[mi][ni] = __builtin_amdgcn_mfma_f32_16x16x32_bf16(af[mi], bfr[ni], acc[mi][ni], 0, 0, 0);
    }
    __syncthreads();
  }

  float bval[4];
#pragma unroll
  for (int ni = 0; ni < 4; ++ni)
    bval[ni] = bias[(size_t)head * NTOT + n0 + w_n * 64 + ni * 16 + l16];

#pragma unroll
  for (int mi = 0; mi < 4; ++mi) {
#pragma unroll
    for (int r = 0; r < 4; ++r) {
      int m = w_m * 64 + mi * 16 + q * 4 + r;
      if (m < rows) {
        int p = row0 + m;
#pragma unroll
        for (int ni = 0; ni < 4; ++ni) {
          int n = n0 + w_n * 64 + ni * 16 + l16;
          float v = acc[mi][ni][r] + bval[ni];
          v = v > 0.f ? v : 0.f;
          Hout[(size_t)p * NTOT + n] = f2bf(v);
        }
      }
    }
  }
}

// ---------------- K2: gemm1 (blocks 0..159) || W2 transpose (160..2207) ------
__global__ __launch_bounds__(256) void k2_kernel(const unsigned short* __restrict__ Xb,
                                                 const int* __restrict__ order,
                                                 const int* __restrict__ offsets,
                                                 const unsigned short* __restrict__ W1t,
                                                 const float* __restrict__ b1,
                                                 unsigned short* __restrict__ Hb,
                                                 const float* __restrict__ W2,
                                                 unsigned short* __restrict__ W2t) {
  __shared__ __align__(16) unsigned char smem[32768];
  int b = blockIdx.x;
  if (b < 160) {
    gemm1_body(Xb, W1t, b1, offsets, order, Hb,
               (unsigned short*)smem, (unsigned short*)(smem + 16384),
               b & 3, b >> 2);
  } else {
    transpose64(W2, W2t, HID, OUT_F, b - 160, OUT_F / 64, HID / 64,
                (float(*)[65])smem);
  }
}

// ---------------- K3: gemm2, 128x128, BK=64, dbuf + COUNTED vmcnt pipeline ---
// T4 recipe: raw s_barrier (no vmcnt(0) drain) + counted s_waitcnt vmcnt(8) so
// tile t+1's 8 global_load_lds stay in flight across the barrier while tile t
// is computed. One explicit vmcnt(0) before the prologue pins the count
// (drains the order[]-gather VMEM loads). sched_barrier(0) fences stop the
// compiler hoisting ds_reads / DMA issues across the raw barriers (rule 18).
// Hazards: iter t writes buf[(t+1)&1], last computed at t-1 and sealed by the
// end-of-iter barrier; compute(t) reads buf[t&1], certified by vmcnt(8)+barrier.
__global__ __launch_bounds__(256) void gemm2_kernel(const unsigned short* __restrict__ A,
                                                    const unsigned short* __restrict__ Wt,
                                                    const float* __restrict__ bias,
                                                    const int* __restrict__ offsets,
                                                    const int* __restrict__ order,
                                                    float* __restrict__ Out) {
  constexpr int K = HID, NTOT = OUT_F, BK = 64, NT = K / BK;  // NT = 8
  __shared__ __align__(16) unsigned short As[2][128 * BK];
  __shared__ __align__(16) unsigned short Bs[2][128 * BK];

  int head, row0, rows;
  if (!resolve_head(offsets, blockIdx.y, head, row0, rows)) return;
  int n0 = blockIdx.x * 128;
  const unsigned short* Bh = Wt + (size_t)head * (size_t)NTOT * K;

  int tid = threadIdx.x;
  int wave = tid >> 6;
  int lane = tid & 63;
  int q = lane >> 4;
  int l16 = lane & 15;
  int w_m = wave >> 1, w_n = wave & 1;

  int srow = lane >> 3;
  int seg = lane & 7;
  int segl = seg ^ srow;

  const unsigned short* aptr[4];
  const unsigned short* bptr[4];
#pragma unroll
  for (int i = 0; i < 4; ++i) {
    int rl = wave * 32 + i * 8 + srow;
    bptr[i] = Bh + (size_t)(n0 + rl) * K + segl * 8;
    int pr = row0 + min(rl, rows - 1);
    aptr[i] = A + (size_t)pr * K + segl * 8;
  }

  f32x4 acc[4][4];
#pragma unroll
  for (int i = 0; i < 4; ++i)
#pragma unroll
    for (int j = 0; j < 4; ++j) acc[i][j] = (f32x4){0.f, 0.f, 0.f, 0.f};

  // pin vmcnt counting: drain the order[] gather loads (and anything hoisted)
  __builtin_amdgcn_sched_barrier(0);
  asm volatile("s_waitcnt vmcnt(0)" ::: "memory");
  __builtin_amdgcn_sched_barrier(0);

  // prologue: stage tile 0 into buffer 0 (8 outstanding after this)
#pragma unroll
  for (int i = 0; i < 4; ++i) {
    __builtin_amdgcn_global_load_lds((gu32*)bptr[i], (lu32*)(&Bs[0][wave * 2048 + i * 512]), 16, 0, 0);
    bptr[i] += BK;
    __builtin_amdgcn_global_load_lds((gu32*)aptr[i], (lu32*)(&As[0][wave * 2048 + i * 512]), 16, 0, 0);
    aptr[i] += BK;
  }

#pragma unroll
  for (int t = 0; t < NT; ++t) {
    const int cur = t & 1;
    if (t + 1 < NT) {
      // issue tile t+1 into the other buffer (16 outstanding), then wait for
      // tile t's 8 only — tile t+1 stays in flight across the whole compute.
#pragma unroll
      for (int i = 0; i < 4; ++i) {
        __builtin_amdgcn_global_load_lds((gu32*)bptr[i], (lu32*)(&Bs[cur ^ 1][wave * 2048 + i * 512]), 16, 0, 0);
        bptr[i] += BK;
        __builtin_amdgcn_global_load_lds((gu32*)aptr[i], (lu32*)(&As[cur ^ 1][wave * 2048 + i * 512]), 16, 0, 0);
        aptr[i] += BK;
      }
      __builtin_amdgcn_sched_barrier(0);
      asm volatile("s_waitcnt vmcnt(8)" ::: "memory");
    } else {
      __builtin_amdgcn_sched_barrier(0);
      asm volatile("s_waitcnt vmcnt(0)" ::: "memory");
    }
    __builtin_amdgcn_s_barrier();          // tile t fully in LDS for all waves
    __builtin_amdgcn_sched_barrier(0);
#pragma unroll
    for (int kk = 0; kk < 2; ++kk) {
      bf16x8 af[4], bfr[4];
#pragma unroll
      for (int i = 0; i < 4; ++i) {
        int ps = ((kk * 4 + q) ^ (l16 & 7)) * 8;
        af[i] = *(const bf16x8*)(&As[cur][(w_m * 64 + i * 16 + l16) * 64 + ps]);
        bfr[i] = *(const bf16x8*)(&Bs[cur][(w_n * 64 + i * 16 + l16) * 64 + ps]);
      }
#pragma unroll
      for (int mi = 0; mi < 4; ++mi)
#pragma unroll
        for (int ni = 0; ni < 4; ++ni)
          acc[mi][ni] = __builtin_amdgcn_mfma_f32_16x16x32_bf16(af[mi], bfr[ni], acc[mi][ni], 0, 0, 0);
    }
    __builtin_amdgcn_sched_barrier(0);
    __builtin_amdgcn_s_barrier();          // seal buf cur before t+1 overwrites
  }

  float bval[4];
#pragma unroll
  for (int ni = 0; ni < 4; ++ni)
    bval[ni] = bias[(size_t)head * NTOT + n0 + w_n * 64 + ni * 16 + l16];

#pragma unroll
  for (int mi = 0; mi < 4; ++mi) {
#pragma unroll
    for (int r = 0; r < 4; ++r) {
      int m = w_m * 64 + mi * 16 + q * 4 + r;
      if (m < rows) {
        int rg = order[row0 + m];
#pragma unroll
        for (int ni = 0; ni < 4; ++ni) {
          int n = n0 + w_n * 64 + ni * 16 + l16;
          Out[(size_t)rg * NTOT + n] = acc[mi][ni][r] + bval[ni];
        }
      }
    }
  }
}

extern "C" void kernel_launch(void* const* d_in, const int* in_sizes, int n_in,
                              void* d_out, int out_size, void* d_ws, size_t ws_size,
                              hipStream_t stream) {
  const float* X = (const float*)d_in[0];
  const int* idxh = (const int*)d_in[1];
  const float* W1 = (const float*)d_in[2];
  const float* b1 = (const float*)d_in[3];
  const float* W2 = (const float*)d_in[4];
  const float* b2 = (const float*)d_in[5];
  float* out = (float*)d_out;

  char* ws = (char*)d_ws;
  int* order = (int*)ws;                     ws += (size_t)BATCH * 4;
  int* offsets = (int*)ws;                   ws += 64;
  unsigned short* Xb = (unsigned short*)ws;  ws += (size_t)BATCH * IN_F * 2;
  unsigned short* W1t = (unsigned short*)ws; ws += (size_t)N_HEADS * IN_F * HID * 2;
  unsigned short* W2t = (unsigned short*)ws; ws += (size_t)N_HEADS * HID * OUT_F * 2;
  unsigned short* Hb = (unsigned short*)ws;  ws += (size_t)BATCH * HID * 2;

  k1_kernel<<<dim3(385), dim3(256), 0, stream>>>(idxh, X, Xb, order, offsets, W1, W1t);
  k2_kernel<<<dim3(2208), dim3(256), 0, stream>>>(Xb, order, offsets, W1t, b1, Hb, W2, W2t);

  constexpr int MT = BATCH / 128 + N_HEADS;
  gemm2_kernel<<<dim3(OUT_F / 128, MT), dim3(256), 0, stream>>>(
      Hb, W2t, b2, offsets, order, out);
}